// Round 7
// baseline (10324.487 us; speedup 1.0000x reference)
//
#include <hip/hip_runtime.h>
#include <math.h>

using short8 = __attribute__((ext_vector_type(8))) short;
using f32x4  = __attribute__((ext_vector_type(4))) float;

struct Tab8 { long o[8]; };

__device__ __forceinline__ unsigned short f2bf(float f) {
    unsigned u = __builtin_bit_cast(unsigned, f);
    unsigned r = u + 0x7FFFu + ((u >> 16) & 1u);   // RNE
    return (unsigned short)(r >> 16);
}
__device__ __forceinline__ float bf2f(unsigned short h) {
    unsigned u = ((unsigned)h) << 16;
    return __builtin_bit_cast(float, u);
}

// ---------------------------------------------------------------------------
// Conv weight prep: fp32 OIHW(3x3) -> split-bf16 [cib16][Opad][tap*32 + q]
// ---------------------------------------------------------------------------
struct WDesc { const float* w; int Ci, O, Opad; long off; };
struct WDescs { WDesc d[18]; };

__global__ __launch_bounds__(256) void prep_w_k(WDescs ds, unsigned short* wp)
{
    const WDesc d = ds.d[blockIdx.y];
    const int ncib = (d.Ci + 15) >> 4;
    const int n = ncib * d.Opad * 288;
    const int idx = blockIdx.x * 256 + threadIdx.x;
    if (idx >= n) return;
    const int within = idx % 288;
    const int o = (idx / 288) % d.Opad;
    const int cib = idx / (288 * d.Opad);
    const int t = within >> 5, q = within & 31;
    const int ci = (cib << 4) + (q & 15);
    float v = 0.0f;
    if (o < d.O && ci < d.Ci) v = d.w[((long)o * d.Ci + ci) * 9 + t];
    const unsigned short hi = f2bf(v);
    const unsigned short lo = f2bf(v - bf2f(hi));
    wp[d.off + idx] = (q < 16) ? hi : lo;
}

// DCN weight prep: fp32 [64][576] -> split-bf16 [kb=36][o=64][q=32]
__global__ __launch_bounds__(256) void prep_dcnw_k(const float* __restrict__ w,
                                                   unsigned short* __restrict__ out)
{
    const int idx = blockIdx.x * 256 + threadIdx.x;
    if (idx >= 36 * 64 * 32) return;
    const int q = idx & 31, o = (idx >> 5) & 63, kb = idx >> 11;
    const float v = w[o * 576 + kb * 16 + (q & 15)];
    const unsigned short hi = f2bf(v);
    out[idx] = (q < 16) ? hi : f2bf(v - bf2f(hi));
}

// ---------------------------------------------------------------------------
// Split-bf16 MFMA conv3x3, SAME, NCHW, per-batch offset tables.
// act: 0=none 1=relu 2=lrelu(0.01). Block: 4 waves, 64 out-ch x 16x16 px.
// ---------------------------------------------------------------------------
__global__ __launch_bounds__(256, 2) void conv_mfma_k(
    const float* __restrict__ in1, Tab8 t1, int cin1,
    const float* __restrict__ in2, Tab8 t2, int cin2,
    const unsigned short* __restrict__ wp,
    const float* __restrict__ bias,
    const float* __restrict__ res, Tab8 trr, int hasres,
    float* __restrict__ out, Tab8 to,
    int O, int H, int W, int act)
{
    __shared__ unsigned short in_t[12960];   // [18*18 px][40 stride, 32 used]
    __shared__ unsigned short w_t[18944];    // [64 co][296 stride, 288 used]
    const int tid = threadIdx.x;
    const int b = blockIdx.z;
    const int Opad = gridDim.y << 6;
    const int cobase = blockIdx.y << 6;
    const int tilesX = (W + 15) >> 4;
    const int tx = blockIdx.x % tilesX, ty = blockIdx.x / tilesX;
    const int x0 = tx << 4, y0 = ty << 4;
    const int HW = H * W;
    const int cin_tot = cin1 + cin2;
    const int ncib = (cin_tot + 15) >> 4;
    const int wv = tid >> 6, lane = tid & 63;
    const int lxx = lane & 15, kb = lane >> 4;
    const long o1 = t1.o[b], o2 = t2.o[b];

    f32x4 acc[4][4];
    #pragma unroll
    for (int i = 0; i < 4; ++i)
        #pragma unroll
        for (int j = 0; j < 4; ++j)
            acc[i][j] = (f32x4){0.f, 0.f, 0.f, 0.f};

    for (int cib = 0; cib < ncib; ++cib) {
        __syncthreads();
        const unsigned short* slab = wp + ((long)cib * Opad + cobase) * 288;
        #pragma unroll
        for (int i = 0; i < 9; ++i) {
            const int c = tid + (i << 8);
            const int row = c / 36, col = c - row * 36;
            *(short8*)&w_t[row * 296 + (col << 3)] =
                *(const short8*)(slab + row * 288 + (col << 3));
        }
        // ---- stage input halo: 2592 items (18y x 18x x 8 ch-pairs), all thr
        for (int it = 0; it < 11; ++it) {
            const int idx = it * 256 + tid;
            if (idx < 2592) {
                const int xx = idx % 18;
                const int yy = (idx / 18) % 18;
                const int rp = idx / 324;
                const int g = (cib << 4) + (rp << 1);
                const int gy = y0 - 1 + yy;
                const int gx = x0 - 1 + xx;
                const bool ok = (gy >= 0) && (gy < H) && (gx >= 0) && (gx < W);
                float v0 = 0.f, v1 = 0.f;
                if (ok) {
                    const long pix = (long)gy * W + gx;
                    if (g < cin_tot)
                        v0 = (g < cin1) ? in1[o1 + (long)g * HW + pix]
                                        : in2[o2 + (long)(g - cin1) * HW + pix];
                    if (g + 1 < cin_tot)
                        v1 = (g + 1 < cin1) ? in1[o1 + (long)(g + 1) * HW + pix]
                                            : in2[o2 + (long)(g + 1 - cin1) * HW + pix];
                }
                const unsigned short h0 = f2bf(v0), h1 = f2bf(v1);
                const unsigned short l0 = f2bf(v0 - bf2f(h0));
                const unsigned short l1 = f2bf(v1 - bf2f(h1));
                unsigned short* base = &in_t[(yy * 18 + xx) * 40];
                *(unsigned*)(base + (rp << 1))      = (unsigned)h0 | ((unsigned)h1 << 16);
                *(unsigned*)(base + 16 + (rp << 1)) = (unsigned)l0 | ((unsigned)l1 << 16);
            }
        }
        __syncthreads();
        #pragma unroll
        for (int ky = 0; ky < 3; ++ky) {
            #pragma unroll
            for (int kx = 0; kx < 3; ++kx) {
                const int tap = ky * 3 + kx;
                short8 a[4], b1[4], b2[4];
                #pragma unroll
                for (int mt = 0; mt < 4; ++mt)
                    a[mt] = *(const short8*)&w_t[(mt * 16 + lxx) * 296 + tap * 32 + kb * 8];
                #pragma unroll
                for (int rr = 0; rr < 4; ++rr) {
                    const int pbase = ((wv * 4 + rr + ky) * 18 + lxx + kx) * 40;
                    b1[rr] = *(const short8*)&in_t[pbase + kb * 8];
                    b2[rr] = *(const short8*)&in_t[pbase + (kb ^ 2) * 8];
                }
                #pragma unroll
                for (int mt = 0; mt < 4; ++mt)
                    #pragma unroll
                    for (int rr = 0; rr < 4; ++rr) {
                        acc[mt][rr] = __builtin_amdgcn_mfma_f32_16x16x32_bf16(
                            a[mt], b1[rr], acc[mt][rr], 0, 0, 0);
                        acc[mt][rr] = __builtin_amdgcn_mfma_f32_16x16x32_bf16(
                            a[mt], b2[rr], acc[mt][rr], 0, 0, 0);
                    }
            }
        }
    }

    const int x = x0 + lxx;
    const bool xok = (x < W);
    const long ob = to.o[b], rb = trr.o[b];
    #pragma unroll
    for (int mt = 0; mt < 4; ++mt) {
        const int col0 = cobase + mt * 16 + kb * 4;
        float bvv[4];
        #pragma unroll
        for (int j = 0; j < 4; ++j)
            bvv[j] = (col0 + j < O) ? bias[col0 + j] : 0.0f;
        #pragma unroll
        for (int rr = 0; rr < 4; ++rr) {
            const int y = y0 + wv * 4 + rr;
            if (y >= H) continue;
            #pragma unroll
            for (int j = 0; j < 4; ++j) {
                const int coj = col0 + j;
                if (coj >= O || !xok) continue;
                float v = acc[mt][rr][j] + bvv[j];
                if (hasres) v += res[rb + (long)coj * HW + (long)y * W + x];
                if (act == 1) v = fmaxf(v, 0.0f);
                else if (act == 2) v = (v >= 0.0f) ? v : 0.01f * v;
                out[ob + (long)coj * HW + (long)y * W + x] = v;
            }
        }
    }
}

// ---------------------------------------------------------------------------
// MaxPool2d(3,2,1) + LeakyReLU
// ---------------------------------------------------------------------------
__global__ __launch_bounds__(256) void pool_lrelu_k(
    const float* __restrict__ in, float* __restrict__ out, int H, int W)
{
    const int Ho = H / 2, Wo = W / 2;
    const int n = blockIdx.y;
    const int i = blockIdx.x * 256 + threadIdx.x;
    if (i >= Ho * Wo) return;
    const int ho = i / Wo, wo = i % Wo;
    const float* p = in + (long)n * H * W;
    float m = -1e30f;
    #pragma unroll
    for (int dy = 0; dy < 3; ++dy) {
        const int y = 2 * ho - 1 + dy;
        if (y < 0 || y >= H) continue;
        #pragma unroll
        for (int dx = 0; dx < 3; ++dx) {
            const int x = 2 * wo - 1 + dx;
            if (x < 0 || x >= W) continue;
            m = fmaxf(m, p[y * W + x]);
        }
    }
    out[(long)n * Ho * Wo + i] = (m >= 0.0f) ? m : 0.01f * m;
}

// Bilinear 2x upsample (half-pixel, edge clamp) then *2.0
__global__ __launch_bounds__(256) void resize2x_k(
    const float* __restrict__ in, float* __restrict__ out, int H, int W)
{
    const int Ho = 2 * H, Wo = 2 * W;
    const int n = blockIdx.y;
    const int i = blockIdx.x * 256 + threadIdx.x;
    if (i >= Ho * Wo) return;
    const int ho = i / Wo, wo = i % Wo;
    float cy = fminf(fmaxf(0.5f * (ho + 0.5f) - 0.5f, 0.0f), (float)(H - 1));
    float cx = fminf(fmaxf(0.5f * (wo + 0.5f) - 0.5f, 0.0f), (float)(W - 1));
    const int y0 = (int)cy, x0 = (int)cx;
    const int y1 = min(y0 + 1, H - 1), x1 = min(x0 + 1, W - 1);
    const float fy = cy - y0, fx = cx - x0;
    const float* p = in + (long)n * H * W;
    const float v = (1.0f - fy) * ((1.0f - fx) * p[y0 * W + x0] + fx * p[y0 * W + x1])
                  + fy * ((1.0f - fx) * p[y1 * W + x0] + fx * p[y1 * W + x1]);
    out[(long)n * Ho * Wo + i] = 2.0f * v;
}

// ---------------------------------------------------------------------------
// NCHW (strided view slot) -> NHWC [HW][64] transpose, per batch elem.
// ---------------------------------------------------------------------------
__global__ __launch_bounds__(256) void nhwc_k(
    const float* __restrict__ src, Tab8 ts, float* __restrict__ dst,
    long dstride, int HW)
{
    __shared__ float t[64][65];
    const int tid = threadIdx.x;
    const int vb = blockIdx.y;
    const int pos0 = blockIdx.x * 64;
    const float* s = src + ts.o[vb];
    float* d = dst + (long)vb * dstride;
    const int l = tid & 63, q = tid >> 6;
    #pragma unroll
    for (int i = 0; i < 16; ++i) {
        const int c = q * 16 + i;
        t[c][l] = s[(long)c * HW + pos0 + l];
    }
    __syncthreads();
    #pragma unroll
    for (int i = 0; i < 16; ++i) {
        const int p = q * 16 + i;
        d[(long)(pos0 + p) * 64 + l] = t[l][p];
    }
}

// ---------------------------------------------------------------------------
// Modulated deformable conv v2 on NHWC x. Phase A: shared records (SoA LDS);
// phase B: 8-ch vectorized gather -> split-bf16 val; phase C: MFMA K=576
// (A-frags straight from L2). Direct write into laps slot.
// ---------------------------------------------------------------------------
__global__ __launch_bounds__(256, 2) void dcn_mfma_k(
    const float* __restrict__ xT, long xtstride,     // [vb][HW][64]
    const float* __restrict__ om, long omstride,
    const unsigned short* __restrict__ wp,           // [36][64][32]
    const float* __restrict__ bias,
    float* __restrict__ outb, Tab8 toff,
    int H, int W)
{
    __shared__ unsigned short valb[9][32][40];       // 23,040 B
    __shared__ float rw0[576], rw1[576], rw2[576], rw3[576];
    __shared__ int ridx[576], rdd[576];              // total ~36.9 KB

    const int tid = threadIdx.x;
    const int vb = blockIdx.y;
    const int HW = H * W;
    const int pos0 = blockIdx.x * 32;
    const float* xv = xT + (long)vb * xtstride;
    const float* omv = om + (long)vb * omstride;
    const int lane = tid & 63, wv = tid >> 6;
    const int lxx = lane & 15, kq = lane >> 4;

    f32x4 acc[2];
    acc[0] = (f32x4){0.f, 0.f, 0.f, 0.f};
    acc[1] = (f32x4){0.f, 0.f, 0.f, 0.f};

    for (int gp = 0; gp < 4; ++gp) {
        // ---- phase A: one record per (g2,kk,pos); disjoint from prior C ----
        for (int r = tid; r < 576; r += 256) {
            const int p = r & 31;
            const int gk = r >> 5;
            const int g2 = (gk >= 9) ? 1 : 0;
            const int kk = gk - g2 * 9;
            const int g = gp * 2 + g2;
            const int pos = pos0 + p;
            const int hh = pos / W, ww = pos % W;
            const int ch = g * 9 + kk;
            const float dy = omv[(long)ch * HW + pos];
            const float dx = omv[(long)(72 + ch) * HW + pos];
            const float mv = omv[(long)(144 + ch) * HW + pos];
            const float m = 1.0f / (1.0f + expf(-mv));
            float py = dy + (float)(hh + kk / 3 - 1);
            float px = dx + (float)(ww + kk % 3 - 1);
            py = fminf(fmaxf(py, -8.0f), (float)H + 8.0f);
            px = fminf(fmaxf(px, -8.0f), (float)W + 8.0f);
            const float yf = floorf(py), xf = floorf(px);
            const float wy = py - yf, wx = px - xf;
            const int y0 = (int)yf, x0 = (int)xf;
            const int y1 = y0 + 1, x1 = x0 + 1;
            const bool yv0 = (y0 >= 0) && (y0 < H), yv1 = (y1 >= 0) && (y1 < H);
            const bool xv0_ = (x0 >= 0) && (x0 < W), xv1_ = (x1 >= 0) && (x1 < W);
            const int yc0 = min(max(y0, 0), H - 1), yc1 = min(max(y1, 0), H - 1);
            const int xc0 = min(max(x0, 0), W - 1), xc1 = min(max(x1, 0), W - 1);
            rw0[r] = (yv0 && xv0_) ? (1.f - wy) * (1.f - wx) * m : 0.f;
            rw1[r] = (yv0 && xv1_) ? (1.f - wy) * wx * m : 0.f;
            rw2[r] = (yv1 && xv0_) ? wy * (1.f - wx) * m : 0.f;
            rw3[r] = (yv1 && xv1_) ? wy * wx * m : 0.f;
            ridx[r] = yc0 * W + xc0;
            rdd[r] = (xc1 - xc0) | (((yc1 - yc0) * W) << 8);
        }
        __syncthreads();
        // ---- phase B: vectorized 8-ch gather -> split-bf16 val ----
        for (int r = tid; r < 576; r += 256) {
            const int p = r & 31;
            const int gk = r >> 5;
            const int g2 = (gk >= 9) ? 1 : 0;
            const int kk = gk - g2 * 9;
            const int g = gp * 2 + g2;
            const float w0 = rw0[r], w1 = rw1[r], w2 = rw2[r], w3 = rw3[r];
            const int dd = rdd[r];
            const long b00 = ((long)ridx[r] << 6) + (g << 3);
            const long d01 = (long)(dd & 0xff) << 6;
            const long d10 = (long)(dd >> 8) << 6;
            const float4 aA = *(const float4*)(xv + b00);
            const float4 aB = *(const float4*)(xv + b00 + 4);
            const float4 bA = *(const float4*)(xv + b00 + d01);
            const float4 bB = *(const float4*)(xv + b00 + d01 + 4);
            const float4 cA = *(const float4*)(xv + b00 + d10);
            const float4 cB = *(const float4*)(xv + b00 + d10 + 4);
            const float4 dA = *(const float4*)(xv + b00 + d10 + d01);
            const float4 dB = *(const float4*)(xv + b00 + d10 + d01 + 4);
            const int kb0 = g * 72 + kk;
#define DO_CH(VAL, C) { \
            const float v_ = (VAL); \
            const int k_ = kb0 + 9 * (C); \
            const int kbl_ = (k_ >> 4) - gp * 9; \
            const int q_ = k_ & 15; \
            const unsigned short hi_ = f2bf(v_); \
            valb[kbl_][p][q_] = hi_; \
            valb[kbl_][p][q_ + 16] = f2bf(v_ - bf2f(hi_)); }
            DO_CH(w0 * aA.x + w1 * bA.x + w2 * cA.x + w3 * dA.x, 0)
            DO_CH(w0 * aA.y + w1 * bA.y + w2 * cA.y + w3 * dA.y, 1)
            DO_CH(w0 * aA.z + w1 * bA.z + w2 * cA.z + w3 * dA.z, 2)
            DO_CH(w0 * aA.w + w1 * bA.w + w2 * cA.w + w3 * dA.w, 3)
            DO_CH(w0 * aB.x + w1 * bB.x + w2 * cB.x + w3 * dB.x, 4)
            DO_CH(w0 * aB.y + w1 * bB.y + w2 * cB.y + w3 * dB.y, 5)
            DO_CH(w0 * aB.z + w1 * bB.z + w2 * cB.z + w3 * dB.z, 6)
            DO_CH(w0 * aB.w + w1 * bB.w + w2 * cB.w + w3 * dB.w, 7)
#undef DO_CH
        }
        __syncthreads();
        // ---- phase C: MFMA; A-frags coalesced from global (L2-hot) ----
        #pragma unroll
        for (int kb = 0; kb < 9; ++kb) {
            const short8 a = *(const short8*)(
                wp + ((long)(gp * 9 + kb) * 64 + wv * 16 + lxx) * 32 + kq * 8);
            #pragma unroll
            for (int pt = 0; pt < 2; ++pt) {
                const short8 v1 = *(const short8*)&valb[kb][pt * 16 + lxx][kq * 8];
                const short8 v2 = *(const short8*)&valb[kb][pt * 16 + lxx][(kq ^ 2) * 8];
                acc[pt] = __builtin_amdgcn_mfma_f32_16x16x32_bf16(a, v1, acc[pt], 0, 0, 0);
                acc[pt] = __builtin_amdgcn_mfma_f32_16x16x32_bf16(a, v2, acc[pt], 0, 0, 0);
            }
        }
        __syncthreads();
    }
    float* ov = outb + toff.o[vb];
    #pragma unroll
    for (int pt = 0; pt < 2; ++pt)
        #pragma unroll
        for (int j = 0; j < 4; ++j) {
            const int o = wv * 16 + kq * 4 + j;
            const int p = pt * 16 + lxx;
            ov[(long)o * HW + pos0 + p] = acc[pt][j] + bias[o];
        }
}

// ---------------------------------------------------------------------------
// Host orchestration
// ---------------------------------------------------------------------------
namespace {

struct MOff {
    const unsigned short *c1w; const float* c1b;
    const unsigned short *rw1; const float* rb1;
    const unsigned short *rw2; const float* rb2;
    const unsigned short *c2w; const float* c2b;
};

inline Tab8 tab(long stride) {
    Tab8 t;
    for (int i = 0; i < 8; ++i) t.o[i] = (long)i * stride;
    return t;
}

inline void conv_b(hipStream_t s,
                   const float* i1, Tab8 t1, int c1,
                   const float* i2, Tab8 t2, int c2,
                   const unsigned short* w, const float* bias,
                   const float* res, Tab8 trr, int hasres,
                   float* out, Tab8 to,
                   int O, int Opad, int H, int W, int B, int act)
{
    dim3 grid(((H + 15) / 16) * ((W + 15) / 16), Opad / 64, B);
    conv_mfma_k<<<grid, 256, 0, s>>>(i1, t1, c1, i2, t2, c2, w, bias,
                                     res, trr, hasres, out, to, O, H, W, act);
}

inline void offnetB(hipStream_t s, const MOff& p,
                    const float* cfb, Tab8 tcf, const float* lfb, Tab8 tlf,
                    float* t1, float* u, float* outp, int H, int W, int B)
{
    const long hw = (long)H * W;
    const Tab8 tz = tab(64 * hw);
    conv_b(s, cfb, tcf, 64, lfb, tlf, 64, p.c1w, p.c1b,
           nullptr, tz, 0, t1, tz, 64, 64, H, W, B, 2);
    for (int r = 0; r < 2; ++r) {
        conv_b(s, t1, tz, 64, nullptr, tz, 0, p.rw1, p.rb1,
               nullptr, tz, 0, u, tz, 64, 64, H, W, B, 1);
        conv_b(s, u, tz, 64, nullptr, tz, 0, p.rw2, p.rb2,
               t1, tz, 1, t1, tz, 64, 64, H, W, B, 0);
    }
    conv_b(s, t1, tz, 64, nullptr, tz, 0, p.c2w, p.c2b,
           nullptr, tz, 0, outp, tz, 64, 64, H, W, B, 2);
}

// NHWC transpose + om conv + fused dcn (direct laps write), chunked for ws.
inline void dcnB(hipStream_t s, float* lapbase, Tab8 tlf,
                 const float* feat,
                 const unsigned short* Wom, const float* omb,
                 const unsigned short* Wdcn, const float* dcnb,
                 float* om, float* xt, int H, int W, int VB)
{
    const long hw = (long)H * W;
    const long SZf = 64L * 25600;
    int cmax = (int)((8L * SZf) / (216 * hw));           // om capacity (8 SZ)
    const int cx = (int)((4L * SZf) / (64 * hw));        // xt capacity (4 SZ)
    if (cx < cmax) cmax = cx;
    if (cmax > VB) cmax = VB;
    if (cmax < 1) cmax = 1;
    for (int c0 = 0; c0 < VB; c0 += cmax) {
        const int nc = (VB - c0 < cmax) ? (VB - c0) : cmax;
        Tab8 tfeat = tab(0), tx = tab(0);
        for (int i = 0; i < nc; ++i) {
            tfeat.o[i] = (long)(c0 + i) * 64 * hw;
            tx.o[i]    = tlf.o[c0 + i];
        }
        dim3 gt((int)(hw / 64), nc);
        nhwc_k<<<gt, 256, 0, s>>>(lapbase, tx, xt, 64 * hw, (int)hw);
        conv_b(s, feat, tfeat, 64, nullptr, tfeat, 0, Wom, omb,
               nullptr, tfeat, 0, om, tab(216 * hw), 216, 256, H, W, nc, 0);
        dim3 gd((int)(hw / 32), nc);
        dcn_mfma_k<<<gd, 256, 0, s>>>(xt, 64 * hw, om, 216 * hw, Wdcn, dcnb,
                                      lapbase, tx, H, W);
    }
}

} // namespace

extern "C" void kernel_launch(void* const* d_in, const int* in_sizes, int n_in,
                              void* d_out, int out_size, void* d_ws, size_t ws_size,
                              hipStream_t stream)
{
    (void)in_sizes; (void)n_in; (void)out_size; (void)ws_size;
    const float* P[39];
    for (int k = 0; k < 39; ++k) P[k] = (const float*)d_in[k];
    const float* images = P[0];

    const int HW0 = 160 * 160, HW1 = 80 * 80, HW2 = 40 * 40;
    float* L0 = (float*)d_out;
    float* L1 = L0 + (long)6 * 64 * HW0;
    float* L2 = L1 + (long)6 * 64 * HW1;

    // ---- workspace: 16*SZ floats (~105 MB) + weights (~3.5 MB) ----
    const long SZ = (long)64 * HW0;
    float* ws = (float*)d_ws;
    float* OFF_A = ws;                        // [0, 4SZ)   po chain
    float* OFF_B = ws + 4 * SZ;               // [4, 8SZ)   offnet-stage / XT
    float* POUP  = ws + 8 * SZ;               // [8, 12SZ)  po_up*2; U scratch
    float* T1    = ws + 12 * SZ;              // [12, 16SZ) offnet hidden
    float* U     = POUP;
    float* OM    = ws + 8 * SZ;               // overlays POUP+T1 (8SZ cap)
    float* A     = ws;                        // features phase (6SZ)
    float* Bb    = ws + 6 * SZ;               // features phase (6SZ)
    unsigned short* WP = (unsigned short*)(ws + 16 * SZ);

    // ---- weight prep ----
    const int widx[18] = {1,3,5,7,9,11,13,15,17,19,21,23,25,27,29,31,33,35};
    const int wci[18]  = {3,64,64,64,64,64,64,64,64,128,64,64,64,128,64,64,64,64};
    const int wo_[18]  = {64,64,64,64,64,64,64,64,64,64,64,64,64,64,64,64,64,216};
    WDescs ds;
    long off = 0;
    long woff[18];
    for (int i = 0; i < 18; ++i) {
        const int opad = (wo_[i] + 63) / 64 * 64;
        const int ncib = (wci[i] + 15) / 16;
        ds.d[i].w = P[widx[i]]; ds.d[i].Ci = wci[i]; ds.d[i].O = wo_[i];
        ds.d[i].Opad = opad; ds.d[i].off = off;
        woff[i] = off;
        off += (long)ncib * opad * 288;
    }
    unsigned short* WPD = WP + off;           // dcn weights [36][64][32]
    prep_w_k<<<dim3(1152, 18), 256, 0, stream>>>(ds, WP);
    prep_dcnw_k<<<dim3(288), 256, 0, stream>>>(P[37], WPD);

    const unsigned short* Wc0a  = WP + woff[0];
    const unsigned short* Wc0r1 = WP + woff[1];
    const unsigned short* Wc0r2 = WP + woff[2];
    const unsigned short* Wc0b  = WP + woff[3];
    const unsigned short* Wd11  = WP + woff[4];
    const unsigned short* Wd12  = WP + woff[5];
    const unsigned short* Wd21  = WP + woff[6];
    const unsigned short* Wd22  = WP + woff[7];
    const unsigned short* Wdc   = WP + woff[8];
    MOff offp = {WP + woff[9],  P[20], WP + woff[10], P[22],
                 WP + woff[11], P[24], WP + woff[12], P[26]};
    MOff mrgp = {WP + woff[13], P[28], WP + woff[14], P[30],
                 WP + woff[15], P[32], WP + woff[16], P[34]};
    const unsigned short* Wom = WP + woff[17];
    const float* dcn_om_b = P[36];
    const float* dcn_b = P[38];

    // ---------------- feature extraction (B = 6, contiguous) --------------
    const Tab8 ti = tab((long)3 * HW0);
    const Tab8 t60 = tab((long)64 * HW0);
    const Tab8 t61 = tab((long)64 * HW1);
    conv_b(stream, images, ti, 3, nullptr, t60, 0, Wc0a, P[2],
           nullptr, t60, 0, A, t60, 64, 64, 160, 160, 6, 0);
    conv_b(stream, A, t60, 64, nullptr, t60, 0, Wc0r1, P[4],
           nullptr, t60, 0, Bb, t60, 64, 64, 160, 160, 6, 1);
    conv_b(stream, Bb, t60, 64, nullptr, t60, 0, Wc0r2, P[6],
           A, t60, 1, A, t60, 64, 64, 160, 160, 6, 0);
    conv_b(stream, A, t60, 64, nullptr, t60, 0, Wc0b, P[8],
           nullptr, t60, 0, L0, t60, 64, 64, 160, 160, 6, 2);

    conv_b(stream, L0, t60, 64, nullptr, t60, 0, Wd11, P[10],
           nullptr, t60, 0, Bb, t60, 64, 64, 160, 160, 6, 1);
    conv_b(stream, Bb, t60, 64, nullptr, t60, 0, Wd12, P[12],
           L0, t60, 1, A, t60, 64, 64, 160, 160, 6, 0);
    conv_b(stream, A, t60, 64, nullptr, t60, 0, Wd21, P[14],
           nullptr, t60, 0, Bb, t60, 64, 64, 160, 160, 6, 1);
    conv_b(stream, Bb, t60, 64, nullptr, t60, 0, Wd22, P[16],
           A, t60, 1, A, t60, 64, 64, 160, 160, 6, 0);
    conv_b(stream, A, t60, 64, nullptr, t60, 0, Wdc, P[18],
           nullptr, t60, 0, Bb, t60, 64, 64, 160, 160, 6, 0);
    {
        dim3 gp((HW1 + 255) / 256, 6 * 64);
        pool_lrelu_k<<<gp, 256, 0, stream>>>(Bb, L1, 160, 160);
    }
    conv_b(stream, L1, t61, 64, nullptr, t61, 0, Wd11, P[10],
           nullptr, t61, 0, Bb, t61, 64, 64, 80, 80, 6, 1);
    conv_b(stream, Bb, t61, 64, nullptr, t61, 0, Wd12, P[12],
           L1, t61, 1, A, t61, 64, 64, 80, 80, 6, 0);
    conv_b(stream, A, t61, 64, nullptr, t61, 0, Wd21, P[14],
           nullptr, t61, 0, Bb, t61, 64, 64, 80, 80, 6, 1);
    conv_b(stream, Bb, t61, 64, nullptr, t61, 0, Wd22, P[16],
           A, t61, 1, A, t61, 64, 64, 80, 80, 6, 0);
    conv_b(stream, A, t61, 64, nullptr, t61, 0, Wdc, P[18],
           nullptr, t61, 0, Bb, t61, 64, 64, 80, 80, 6, 0);
    {
        dim3 gp((HW2 + 255) / 256, 6 * 64);
        pool_lrelu_k<<<gp, 256, 0, stream>>>(Bb, L2, 80, 80);
    }

    // ---------------- view loop: batched {0,1}, then {2} -------------------
    const int cv = 1;
    for (int pass = 0; pass < 2; ++pass) {
        const int vs01[2] = {0, 1};
        const int vs2[1] = {2};
        const int* vlist = pass ? vs2 : vs01;
        const int nv = pass ? 1 : 2;
        const int VB = nv * 2;

        Tab8 tcf2 = tab(0), tlf2 = tab(0), tcf1 = tab(0), tlf1 = tab(0),
             tcf0 = tab(0), tlf0 = tab(0);
        for (int i = 0; i < VB; ++i) {
            const int v = vlist[i >> 1], b = i & 1;
            tlf2.o[i] = ((long)b * 3 + v)  * 64 * HW2;
            tcf2.o[i] = ((long)b * 3 + cv) * 64 * HW2;
            tlf1.o[i] = ((long)b * 3 + v)  * 64 * HW1;
            tcf1.o[i] = ((long)b * 3 + cv) * 64 * HW1;
            tlf0.o[i] = ((long)b * 3 + v)  * 64 * HW0;
            tcf0.o[i] = ((long)b * 3 + cv) * 64 * HW0;
        }
        // ---- level 2 (40x40) ----
        offnetB(stream, offp, L2, tcf2, L2, tlf2, T1, U, OFF_A, 40, 40, VB);
        dcnB(stream, L2, tlf2, OFF_A, Wom, dcn_om_b, WPD, dcn_b,
             OM, OFF_B, 40, 40, VB);
        // ---- level 1 (80x80) ----
        offnetB(stream, offp, L1, tcf1, L1, tlf1, T1, U, OFF_B, 80, 80, VB);
        {
            dim3 gr((HW1 + 255) / 256, VB * 64);
            resize2x_k<<<gr, 256, 0, stream>>>(OFF_A, POUP, 40, 40);
        }
        offnetB(stream, mrgp, OFF_B, tab((long)64 * HW1), POUP, tab((long)64 * HW1),
                T1, U, OFF_A, 80, 80, VB);
        dcnB(stream, L1, tlf1, OFF_A, Wom, dcn_om_b, WPD, dcn_b,
             OM, OFF_B, 80, 80, VB);
        // ---- level 0 (160x160) ----
        offnetB(stream, offp, L0, tcf0, L0, tlf0, T1, U, OFF_B, 160, 160, VB);
        {
            dim3 gr((HW0 + 255) / 256, VB * 64);
            resize2x_k<<<gr, 256, 0, stream>>>(OFF_A, POUP, 80, 80);
        }
        offnetB(stream, mrgp, OFF_B, tab((long)64 * HW0), POUP, tab((long)64 * HW0),
                T1, U, OFF_A, 160, 160, VB);
        dcnB(stream, L0, tlf0, OFF_A, Wom, dcn_om_b, WPD, dcn_b,
             OM, OFF_B, 160, 160, VB);
    }
}

// Round 8
// 9485.086 us; speedup vs baseline: 1.0885x; 1.0885x over previous
//
#include <hip/hip_runtime.h>
#include <math.h>

using short8 = __attribute__((ext_vector_type(8))) short;
using f32x4  = __attribute__((ext_vector_type(4))) float;

struct Tab8 { long o[8]; };

__device__ __forceinline__ unsigned short f2bf(float f) {
    unsigned u = __builtin_bit_cast(unsigned, f);
    unsigned r = u + 0x7FFFu + ((u >> 16) & 1u);   // RNE
    return (unsigned short)(r >> 16);
}
__device__ __forceinline__ float bf2f(unsigned short h) {
    unsigned u = ((unsigned)h) << 16;
    return __builtin_bit_cast(float, u);
}

// ---------------------------------------------------------------------------
// Conv weight prep: fp32 OIHW(3x3) -> split-bf16 [cib16][tap][Opad][q32]
// q<16: hi(ci=cib*16+q), q>=16: lo. Zero padded. Per (cib,tap): 64 co x 32
// contiguous -> A-frag reads are 1KB/wave coalesced.
// ---------------------------------------------------------------------------
struct WDesc { const float* w; int Ci, O, Opad; long off; };
struct WDescs { WDesc d[18]; };

__global__ __launch_bounds__(256) void prep_w_k(WDescs ds, unsigned short* wp)
{
    const WDesc d = ds.d[blockIdx.y];
    const int ncib = (d.Ci + 15) >> 4;
    const int n = ncib * d.Opad * 288;
    const int idx = blockIdx.x * 256 + threadIdx.x;
    if (idx >= n) return;
    const int q = idx & 31;
    const int rest = idx >> 5;
    const int o = rest % d.Opad;
    const int rest2 = rest / d.Opad;
    const int t = rest2 % 9;
    const int cib = rest2 / 9;
    const int ci = (cib << 4) + (q & 15);
    float v = 0.0f;
    if (o < d.O && ci < d.Ci) v = d.w[((long)o * d.Ci + ci) * 9 + t];
    const unsigned short hi = f2bf(v);
    const unsigned short lo = f2bf(v - bf2f(hi));
    wp[d.off + idx] = (q < 16) ? hi : lo;
}

// DCN weight prep: fp32 [64][576] -> split-bf16 [kb=36][o=64][q=32]
__global__ __launch_bounds__(256) void prep_dcnw_k(const float* __restrict__ w,
                                                   unsigned short* __restrict__ out)
{
    const int idx = blockIdx.x * 256 + threadIdx.x;
    if (idx >= 36 * 64 * 32) return;
    const int q = idx & 31, o = (idx >> 5) & 63, kb = idx >> 11;
    const float v = w[o * 576 + kb * 16 + (q & 15)];
    const unsigned short hi = f2bf(v);
    out[idx] = (q < 16) ? hi : f2bf(v - bf2f(hi));
}

// ---------------------------------------------------------------------------
// Split-bf16 MFMA conv3x3, SAME, NCHW, per-batch offset tables.
// A-frags read directly from global (L2-hot) -- no weight LDS tile.
// act: 0=none 1=relu 2=lrelu(0.01). Block: 4 waves, 64 out-ch x 16x16 px.
// ---------------------------------------------------------------------------
__global__ __launch_bounds__(256, 3) void conv_mfma_k(
    const float* __restrict__ in1, Tab8 t1, int cin1,
    const float* __restrict__ in2, Tab8 t2, int cin2,
    const unsigned short* __restrict__ wp,
    const float* __restrict__ bias,
    const float* __restrict__ res, Tab8 trr, int hasres,
    float* __restrict__ out, Tab8 to,
    int O, int H, int W, int act)
{
    __shared__ unsigned short in_t[12960];   // [18*18 px][40 stride, 32 used]
    const int tid = threadIdx.x;
    const int b = blockIdx.z;
    const int Opad = gridDim.y << 6;
    const int cobase = blockIdx.y << 6;
    const int tilesX = (W + 15) >> 4;
    const int tx = blockIdx.x % tilesX, ty = blockIdx.x / tilesX;
    const int x0 = tx << 4, y0 = ty << 4;
    const int HW = H * W;
    const int cin_tot = cin1 + cin2;
    const int ncib = (cin_tot + 15) >> 4;
    const int wv = tid >> 6, lane = tid & 63;
    const int lxx = lane & 15, kb = lane >> 4;
    const long o1 = t1.o[b], o2 = t2.o[b];

    f32x4 acc[4][4];
    #pragma unroll
    for (int i = 0; i < 4; ++i)
        #pragma unroll
        for (int j = 0; j < 4; ++j)
            acc[i][j] = (f32x4){0.f, 0.f, 0.f, 0.f};

    for (int cib = 0; cib < ncib; ++cib) {
        __syncthreads();
        // ---- stage input halo: 18x18 px, 16 real ch -> [hi(16)|lo(16)] ----
        if (tid < 144) {
            const int yy = tid >> 3, rp = tid & 7;
            const int g = (cib << 4) + (rp << 1);
            const float* s0 = nullptr;
            const float* s1 = nullptr;
            if (g < cin_tot)
                s0 = (g < cin1) ? in1 + o1 + (long)g * HW
                                : in2 + o2 + (long)(g - cin1) * HW;
            if (g + 1 < cin_tot)
                s1 = (g + 1 < cin1) ? in1 + o1 + (long)(g + 1) * HW
                                    : in2 + o2 + (long)(g + 1 - cin1) * HW;
            const int gy = y0 - 1 + yy;
            const bool yok = (gy >= 0) && (gy < H);
            #pragma unroll
            for (int xx = 0; xx < 18; ++xx) {
                const int gx = x0 - 1 + xx;
                const bool ok = yok && (gx >= 0) && (gx < W);
                const float v0 = (ok && s0) ? s0[gy * W + gx] : 0.0f;
                const float v1 = (ok && s1) ? s1[gy * W + gx] : 0.0f;
                const unsigned short h0 = f2bf(v0), h1 = f2bf(v1);
                const unsigned short l0 = f2bf(v0 - bf2f(h0));
                const unsigned short l1 = f2bf(v1 - bf2f(h1));
                unsigned short* base = &in_t[(yy * 18 + xx) * 40];
                *(unsigned*)(base + (rp << 1))      = (unsigned)h0 | ((unsigned)h1 << 16);
                *(unsigned*)(base + 16 + (rp << 1)) = (unsigned)l0 | ((unsigned)l1 << 16);
            }
        }
        __syncthreads();
        // ---- 9 taps; A-frags from global (coalesced, L2-hot) ----
        const unsigned short* wcib = wp + (long)cib * 9 * Opad * 32;
        #pragma unroll
        for (int ky = 0; ky < 3; ++ky) {
            #pragma unroll
            for (int kx = 0; kx < 3; ++kx) {
                const int tap = ky * 3 + kx;
                const unsigned short* wrow =
                    wcib + ((long)tap * Opad + cobase) * 32;
                short8 a[4], b1[4], b2[4];
                #pragma unroll
                for (int mt = 0; mt < 4; ++mt)
                    a[mt] = *(const short8*)(wrow + (mt * 16 + lxx) * 32 + kb * 8);
                #pragma unroll
                for (int rr = 0; rr < 4; ++rr) {
                    const int pbase = ((wv * 4 + rr + ky) * 18 + lxx + kx) * 40;
                    b1[rr] = *(const short8*)&in_t[pbase + kb * 8];
                    b2[rr] = *(const short8*)&in_t[pbase + (kb ^ 2) * 8];
                }
                #pragma unroll
                for (int mt = 0; mt < 4; ++mt)
                    #pragma unroll
                    for (int rr = 0; rr < 4; ++rr) {
                        acc[mt][rr] = __builtin_amdgcn_mfma_f32_16x16x32_bf16(
                            a[mt], b1[rr], acc[mt][rr], 0, 0, 0);
                        acc[mt][rr] = __builtin_amdgcn_mfma_f32_16x16x32_bf16(
                            a[mt], b2[rr], acc[mt][rr], 0, 0, 0);
                    }
            }
        }
    }

    const int x = x0 + lxx;
    const bool xok = (x < W);
    const long ob = to.o[b], rb = trr.o[b];
    #pragma unroll
    for (int mt = 0; mt < 4; ++mt) {
        const int col0 = cobase + mt * 16 + kb * 4;
        float bvv[4];
        #pragma unroll
        for (int j = 0; j < 4; ++j)
            bvv[j] = (col0 + j < O) ? bias[col0 + j] : 0.0f;
        #pragma unroll
        for (int rr = 0; rr < 4; ++rr) {
            const int y = y0 + wv * 4 + rr;
            if (y >= H) continue;
            #pragma unroll
            for (int j = 0; j < 4; ++j) {
                const int coj = col0 + j;
                if (coj >= O || !xok) continue;
                float v = acc[mt][rr][j] + bvv[j];
                if (hasres) v += res[rb + (long)coj * HW + (long)y * W + x];
                if (act == 1) v = fmaxf(v, 0.0f);
                else if (act == 2) v = (v >= 0.0f) ? v : 0.01f * v;
                out[ob + (long)coj * HW + (long)y * W + x] = v;
            }
        }
    }
}

// ---------------------------------------------------------------------------
// MaxPool2d(3,2,1) + LeakyReLU
// ---------------------------------------------------------------------------
__global__ __launch_bounds__(256) void pool_lrelu_k(
    const float* __restrict__ in, float* __restrict__ out, int H, int W)
{
    const int Ho = H / 2, Wo = W / 2;
    const int n = blockIdx.y;
    const int i = blockIdx.x * 256 + threadIdx.x;
    if (i >= Ho * Wo) return;
    const int ho = i / Wo, wo = i % Wo;
    const float* p = in + (long)n * H * W;
    float m = -1e30f;
    #pragma unroll
    for (int dy = 0; dy < 3; ++dy) {
        const int y = 2 * ho - 1 + dy;
        if (y < 0 || y >= H) continue;
        #pragma unroll
        for (int dx = 0; dx < 3; ++dx) {
            const int x = 2 * wo - 1 + dx;
            if (x < 0 || x >= W) continue;
            m = fmaxf(m, p[y * W + x]);
        }
    }
    out[(long)n * Ho * Wo + i] = (m >= 0.0f) ? m : 0.01f * m;
}

// Bilinear 2x upsample (half-pixel, edge clamp) then *2.0
__global__ __launch_bounds__(256) void resize2x_k(
    const float* __restrict__ in, float* __restrict__ out, int H, int W)
{
    const int Ho = 2 * H, Wo = 2 * W;
    const int n = blockIdx.y;
    const int i = blockIdx.x * 256 + threadIdx.x;
    if (i >= Ho * Wo) return;
    const int ho = i / Wo, wo = i % Wo;
    float cy = fminf(fmaxf(0.5f * (ho + 0.5f) - 0.5f, 0.0f), (float)(H - 1));
    float cx = fminf(fmaxf(0.5f * (wo + 0.5f) - 0.5f, 0.0f), (float)(W - 1));
    const int y0 = (int)cy, x0 = (int)cx;
    const int y1 = min(y0 + 1, H - 1), x1 = min(x0 + 1, W - 1);
    const float fy = cy - y0, fx = cx - x0;
    const float* p = in + (long)n * H * W;
    const float v = (1.0f - fy) * ((1.0f - fx) * p[y0 * W + x0] + fx * p[y0 * W + x1])
                  + fy * ((1.0f - fx) * p[y1 * W + x0] + fx * p[y1 * W + x1]);
    out[(long)n * Ho * Wo + i] = 2.0f * v;
}

// ---------------------------------------------------------------------------
// NCHW (strided view slot) -> NHWC [HW][64] transpose, per batch elem.
// ---------------------------------------------------------------------------
__global__ __launch_bounds__(256) void nhwc_k(
    const float* __restrict__ src, Tab8 ts, float* __restrict__ dst,
    long dstride, int HW)
{
    __shared__ float t[64][65];
    const int tid = threadIdx.x;
    const int vb = blockIdx.y;
    const int pos0 = blockIdx.x * 64;
    const float* s = src + ts.o[vb];
    float* d = dst + (long)vb * dstride;
    const int l = tid & 63, q = tid >> 6;
    #pragma unroll
    for (int i = 0; i < 16; ++i) {
        const int c = q * 16 + i;
        t[c][l] = s[(long)c * HW + pos0 + l];
    }
    __syncthreads();
    #pragma unroll
    for (int i = 0; i < 16; ++i) {
        const int p = q * 16 + i;
        d[(long)(pos0 + p) * 64 + l] = t[l][p];
    }
}

// ---------------------------------------------------------------------------
// Modulated deformable conv v2 on NHWC x. Phase A: shared records (SoA LDS);
// phase B: 8-ch vectorized gather -> split-bf16 val; phase C: MFMA K=576
// (A-frags straight from L2). Direct write into laps slot.
// ---------------------------------------------------------------------------
__global__ __launch_bounds__(256, 2) void dcn_mfma_k(
    const float* __restrict__ xT, long xtstride,     // [vb][HW][64]
    const float* __restrict__ om, long omstride,
    const unsigned short* __restrict__ wp,           // [36][64][32]
    const float* __restrict__ bias,
    float* __restrict__ outb, Tab8 toff,
    int H, int W)
{
    __shared__ unsigned short valb[9][32][40];       // 23,040 B
    __shared__ float rw0[576], rw1[576], rw2[576], rw3[576];
    __shared__ int ridx[576], rdd[576];              // total ~36.9 KB

    const int tid = threadIdx.x;
    const int vb = blockIdx.y;
    const int HW = H * W;
    const int pos0 = blockIdx.x * 32;
    const float* xv = xT + (long)vb * xtstride;
    const float* omv = om + (long)vb * omstride;
    const int lane = tid & 63, wv = tid >> 6;
    const int lxx = lane & 15, kq = lane >> 4;

    f32x4 acc[2];
    acc[0] = (f32x4){0.f, 0.f, 0.f, 0.f};
    acc[1] = (f32x4){0.f, 0.f, 0.f, 0.f};

    for (int gp = 0; gp < 4; ++gp) {
        // ---- phase A: one record per (g2,kk,pos) ----
        for (int r = tid; r < 576; r += 256) {
            const int p = r & 31;
            const int gk = r >> 5;
            const int g2 = (gk >= 9) ? 1 : 0;
            const int kk = gk - g2 * 9;
            const int g = gp * 2 + g2;
            const int pos = pos0 + p;
            const int hh = pos / W, ww = pos % W;
            const int ch = g * 9 + kk;
            const float dy = omv[(long)ch * HW + pos];
            const float dx = omv[(long)(72 + ch) * HW + pos];
            const float mv = omv[(long)(144 + ch) * HW + pos];
            const float m = 1.0f / (1.0f + expf(-mv));
            float py = dy + (float)(hh + kk / 3 - 1);
            float px = dx + (float)(ww + kk % 3 - 1);
            py = fminf(fmaxf(py, -8.0f), (float)H + 8.0f);
            px = fminf(fmaxf(px, -8.0f), (float)W + 8.0f);
            const float yf = floorf(py), xf = floorf(px);
            const float wy = py - yf, wx = px - xf;
            const int y0 = (int)yf, x0 = (int)xf;
            const int y1 = y0 + 1, x1 = x0 + 1;
            const bool yv0 = (y0 >= 0) && (y0 < H), yv1 = (y1 >= 0) && (y1 < H);
            const bool xv0_ = (x0 >= 0) && (x0 < W), xv1_ = (x1 >= 0) && (x1 < W);
            const int yc0 = min(max(y0, 0), H - 1), yc1 = min(max(y1, 0), H - 1);
            const int xc0 = min(max(x0, 0), W - 1), xc1 = min(max(x1, 0), W - 1);
            rw0[r] = (yv0 && xv0_) ? (1.f - wy) * (1.f - wx) * m : 0.f;
            rw1[r] = (yv0 && xv1_) ? (1.f - wy) * wx * m : 0.f;
            rw2[r] = (yv1 && xv0_) ? wy * (1.f - wx) * m : 0.f;
            rw3[r] = (yv1 && xv1_) ? wy * wx * m : 0.f;
            ridx[r] = yc0 * W + xc0;
            rdd[r] = (xc1 - xc0) | (((yc1 - yc0) * W) << 8);
        }
        __syncthreads();
        // ---- phase B: vectorized 8-ch gather -> split-bf16 val ----
        for (int r = tid; r < 576; r += 256) {
            const int p = r & 31;
            const int gk = r >> 5;
            const int g2 = (gk >= 9) ? 1 : 0;
            const int kk = gk - g2 * 9;
            const int g = gp * 2 + g2;
            const float w0 = rw0[r], w1 = rw1[r], w2 = rw2[r], w3 = rw3[r];
            const int dd = rdd[r];
            const long b00 = ((long)ridx[r] << 6) + (g << 3);
            const long d01 = (long)(dd & 0xff) << 6;
            const long d10 = (long)(dd >> 8) << 6;
            const float4 aA = *(const float4*)(xv + b00);
            const float4 aB = *(const float4*)(xv + b00 + 4);
            const float4 bA = *(const float4*)(xv + b00 + d01);
            const float4 bB = *(const float4*)(xv + b00 + d01 + 4);
            const float4 cA = *(const float4*)(xv + b00 + d10);
            const float4 cB = *(const float4*)(xv + b00 + d10 + 4);
            const float4 dA = *(const float4*)(xv + b00 + d10 + d01);
            const float4 dB = *(const float4*)(xv + b00 + d10 + d01 + 4);
            const int kb0 = g * 72 + kk;
#define DO_CH(VAL, C) { \
            const float v_ = (VAL); \
            const int k_ = kb0 + 9 * (C); \
            const int kbl_ = (k_ >> 4) - gp * 9; \
            const int q_ = k_ & 15; \
            const unsigned short hi_ = f2bf(v_); \
            valb[kbl_][p][q_] = hi_; \
            valb[kbl_][p][q_ + 16] = f2bf(v_ - bf2f(hi_)); }
            DO_CH(w0 * aA.x + w1 * bA.x + w2 * cA.x + w3 * dA.x, 0)
            DO_CH(w0 * aA.y + w1 * bA.y + w2 * cA.y + w3 * dA.y, 1)
            DO_CH(w0 * aA.z + w1 * bA.z + w2 * cA.z + w3 * dA.z, 2)
            DO_CH(w0 * aA.w + w1 * bA.w + w2 * cA.w + w3 * dA.w, 3)
            DO_CH(w0 * aB.x + w1 * bB.x + w2 * cB.x + w3 * dB.x, 4)
            DO_CH(w0 * aB.y + w1 * bB.y + w2 * cB.y + w3 * dB.y, 5)
            DO_CH(w0 * aB.z + w1 * bB.z + w2 * cB.z + w3 * dB.z, 6)
            DO_CH(w0 * aB.w + w1 * bB.w + w2 * cB.w + w3 * dB.w, 7)
#undef DO_CH
        }
        __syncthreads();
        // ---- phase C: MFMA; A-frags coalesced from global (L2-hot) ----
        #pragma unroll
        for (int kb = 0; kb < 9; ++kb) {
            const short8 a = *(const short8*)(
                wp + ((long)(gp * 9 + kb) * 64 + wv * 16 + lxx) * 32 + kq * 8);
            #pragma unroll
            for (int pt = 0; pt < 2; ++pt) {
                const short8 v1 = *(const short8*)&valb[kb][pt * 16 + lxx][kq * 8];
                const short8 v2 = *(const short8*)&valb[kb][pt * 16 + lxx][(kq ^ 2) * 8];
                acc[pt] = __builtin_amdgcn_mfma_f32_16x16x32_bf16(a, v1, acc[pt], 0, 0, 0);
                acc[pt] = __builtin_amdgcn_mfma_f32_16x16x32_bf16(a, v2, acc[pt], 0, 0, 0);
            }
        }
        __syncthreads();
    }
    float* ov = outb + toff.o[vb];
    #pragma unroll
    for (int pt = 0; pt < 2; ++pt)
        #pragma unroll
        for (int j = 0; j < 4; ++j) {
            const int o = wv * 16 + kq * 4 + j;
            const int p = pt * 16 + lxx;
            ov[(long)o * HW + pos0 + p] = acc[pt][j] + bias[o];
        }
}

// ---------------------------------------------------------------------------
// Host orchestration
// ---------------------------------------------------------------------------
namespace {

struct MOff {
    const unsigned short *c1w; const float* c1b;
    const unsigned short *rw1; const float* rb1;
    const unsigned short *rw2; const float* rb2;
    const unsigned short *c2w; const float* c2b;
};

inline Tab8 tab(long stride) {
    Tab8 t;
    for (int i = 0; i < 8; ++i) t.o[i] = (long)i * stride;
    return t;
}

inline void conv_b(hipStream_t s,
                   const float* i1, Tab8 t1, int c1,
                   const float* i2, Tab8 t2, int c2,
                   const unsigned short* w, const float* bias,
                   const float* res, Tab8 trr, int hasres,
                   float* out, Tab8 to,
                   int O, int Opad, int H, int W, int B, int act)
{
    dim3 grid(((H + 15) / 16) * ((W + 15) / 16), Opad / 64, B);
    conv_mfma_k<<<grid, 256, 0, s>>>(i1, t1, c1, i2, t2, c2, w, bias,
                                     res, trr, hasres, out, to, O, H, W, act);
}

inline void offnetB(hipStream_t s, const MOff& p,
                    const float* cfb, Tab8 tcf, const float* lfb, Tab8 tlf,
                    float* t1, float* u, float* outp, int H, int W, int B)
{
    const long hw = (long)H * W;
    const Tab8 tz = tab(64 * hw);
    conv_b(s, cfb, tcf, 64, lfb, tlf, 64, p.c1w, p.c1b,
           nullptr, tz, 0, t1, tz, 64, 64, H, W, B, 2);
    for (int r = 0; r < 2; ++r) {
        conv_b(s, t1, tz, 64, nullptr, tz, 0, p.rw1, p.rb1,
               nullptr, tz, 0, u, tz, 64, 64, H, W, B, 1);
        conv_b(s, u, tz, 64, nullptr, tz, 0, p.rw2, p.rb2,
               t1, tz, 1, t1, tz, 64, 64, H, W, B, 0);
    }
    conv_b(s, t1, tz, 64, nullptr, tz, 0, p.c2w, p.c2b,
           nullptr, tz, 0, outp, tz, 64, 64, H, W, B, 2);
}

// NHWC transpose + om conv + fused dcn (direct laps write), chunked for ws.
inline void dcnB(hipStream_t s, float* lapbase, Tab8 tlf,
                 const float* feat,
                 const unsigned short* Wom, const float* omb,
                 const unsigned short* Wdcn, const float* dcnb,
                 float* om, float* xt, int H, int W, int VB)
{
    const long hw = (long)H * W;
    const long SZf = 64L * 25600;
    int cmax = (int)((8L * SZf) / (216 * hw));           // om capacity (8 SZ)
    const int cx = (int)((4L * SZf) / (64 * hw));        // xt capacity (4 SZ)
    if (cx < cmax) cmax = cx;
    if (cmax > VB) cmax = VB;
    if (cmax < 1) cmax = 1;
    for (int c0 = 0; c0 < VB; c0 += cmax) {
        const int nc = (VB - c0 < cmax) ? (VB - c0) : cmax;
        Tab8 tfeat = tab(0), tx = tab(0);
        for (int i = 0; i < nc; ++i) {
            tfeat.o[i] = (long)(c0 + i) * 64 * hw;
            tx.o[i]    = tlf.o[c0 + i];
        }
        dim3 gt((int)(hw / 64), nc);
        nhwc_k<<<gt, 256, 0, s>>>(lapbase, tx, xt, 64 * hw, (int)hw);
        conv_b(s, feat, tfeat, 64, nullptr, tfeat, 0, Wom, omb,
               nullptr, tfeat, 0, om, tab(216 * hw), 216, 256, H, W, nc, 0);
        dim3 gd((int)(hw / 32), nc);
        dcn_mfma_k<<<gd, 256, 0, s>>>(xt, 64 * hw, om, 216 * hw, Wdcn, dcnb,
                                      lapbase, tx, H, W);
    }
}

} // namespace

extern "C" void kernel_launch(void* const* d_in, const int* in_sizes, int n_in,
                              void* d_out, int out_size, void* d_ws, size_t ws_size,
                              hipStream_t stream)
{
    (void)in_sizes; (void)n_in; (void)out_size; (void)ws_size;
    const float* P[39];
    for (int k = 0; k < 39; ++k) P[k] = (const float*)d_in[k];
    const float* images = P[0];

    const int HW0 = 160 * 160, HW1 = 80 * 80, HW2 = 40 * 40;
    float* L0 = (float*)d_out;
    float* L1 = L0 + (long)6 * 64 * HW0;
    float* L2 = L1 + (long)6 * 64 * HW1;

    // ---- workspace: 16*SZ floats (~105 MB) + weights (~3.5 MB) ----
    const long SZ = (long)64 * HW0;
    float* ws = (float*)d_ws;
    float* OFF_A = ws;                        // [0, 4SZ)   po chain
    float* OFF_B = ws + 4 * SZ;               // [4, 8SZ)   offnet-stage / XT
    float* POUP  = ws + 8 * SZ;               // [8, 12SZ)  po_up*2; U scratch
    float* T1    = ws + 12 * SZ;              // [12, 16SZ) offnet hidden
    float* U     = POUP;
    float* OM    = ws + 8 * SZ;               // overlays POUP+T1 (8SZ cap)
    float* A     = ws;                        // features phase (6SZ)
    float* Bb    = ws + 6 * SZ;               // features phase (6SZ)
    unsigned short* WP = (unsigned short*)(ws + 16 * SZ);

    // ---- weight prep ----
    const int widx[18] = {1,3,5,7,9,11,13,15,17,19,21,23,25,27,29,31,33,35};
    const int wci[18]  = {3,64,64,64,64,64,64,64,64,128,64,64,64,128,64,64,64,64};
    const int wo_[18]  = {64,64,64,64,64,64,64,64,64,64,64,64,64,64,64,64,64,216};
    WDescs ds;
    long off = 0;
    long woff[18];
    for (int i = 0; i < 18; ++i) {
        const int opad = (wo_[i] + 63) / 64 * 64;
        const int ncib = (wci[i] + 15) / 16;
        ds.d[i].w = P[widx[i]]; ds.d[i].Ci = wci[i]; ds.d[i].O = wo_[i];
        ds.d[i].Opad = opad; ds.d[i].off = off;
        woff[i] = off;
        off += (long)ncib * opad * 288;
    }
    unsigned short* WPD = WP + off;           // dcn weights [36][64][32]
    prep_w_k<<<dim3(1152, 18), 256, 0, stream>>>(ds, WP);
    prep_dcnw_k<<<dim3(288), 256, 0, stream>>>(P[37], WPD);

    const unsigned short* Wc0a  = WP + woff[0];
    const unsigned short* Wc0r1 = WP + woff[1];
    const unsigned short* Wc0r2 = WP + woff[2];
    const unsigned short* Wc0b  = WP + woff[3];
    const unsigned short* Wd11  = WP + woff[4];
    const unsigned short* Wd12  = WP + woff[5];
    const unsigned short* Wd21  = WP + woff[6];
    const unsigned short* Wd22  = WP + woff[7];
    const unsigned short* Wdc   = WP + woff[8];
    MOff offp = {WP + woff[9],  P[20], WP + woff[10], P[22],
                 WP + woff[11], P[24], WP + woff[12], P[26]};
    MOff mrgp = {WP + woff[13], P[28], WP + woff[14], P[30],
                 WP + woff[15], P[32], WP + woff[16], P[34]};
    const unsigned short* Wom = WP + woff[17];
    const float* dcn_om_b = P[36];
    const float* dcn_b = P[38];

    // ---------------- feature extraction (B = 6, contiguous) --------------
    const Tab8 ti = tab((long)3 * HW0);
    const Tab8 t60 = tab((long)64 * HW0);
    const Tab8 t61 = tab((long)64 * HW1);
    conv_b(stream, images, ti, 3, nullptr, t60, 0, Wc0a, P[2],
           nullptr, t60, 0, A, t60, 64, 64, 160, 160, 6, 0);
    conv_b(stream, A, t60, 64, nullptr, t60, 0, Wc0r1, P[4],
           nullptr, t60, 0, Bb, t60, 64, 64, 160, 160, 6, 1);
    conv_b(stream, Bb, t60, 64, nullptr, t60, 0, Wc0r2, P[6],
           A, t60, 1, A, t60, 64, 64, 160, 160, 6, 0);
    conv_b(stream, A, t60, 64, nullptr, t60, 0, Wc0b, P[8],
           nullptr, t60, 0, L0, t60, 64, 64, 160, 160, 6, 2);

    conv_b(stream, L0, t60, 64, nullptr, t60, 0, Wd11, P[10],
           nullptr, t60, 0, Bb, t60, 64, 64, 160, 160, 6, 1);
    conv_b(stream, Bb, t60, 64, nullptr, t60, 0, Wd12, P[12],
           L0, t60, 1, A, t60, 64, 64, 160, 160, 6, 0);
    conv_b(stream, A, t60, 64, nullptr, t60, 0, Wd21, P[14],
           nullptr, t60, 0, Bb, t60, 64, 64, 160, 160, 6, 1);
    conv_b(stream, Bb, t60, 64, nullptr, t60, 0, Wd22, P[16],
           A, t60, 1, A, t60, 64, 64, 160, 160, 6, 0);
    conv_b(stream, A, t60, 64, nullptr, t60, 0, Wdc, P[18],
           nullptr, t60, 0, Bb, t60, 64, 64, 160, 160, 6, 0);
    {
        dim3 gp((HW1 + 255) / 256, 6 * 64);
        pool_lrelu_k<<<gp, 256, 0, stream>>>(Bb, L1, 160, 160);
    }
    conv_b(stream, L1, t61, 64, nullptr, t61, 0, Wd11, P[10],
           nullptr, t61, 0, Bb, t61, 64, 64, 80, 80, 6, 1);
    conv_b(stream, Bb, t61, 64, nullptr, t61, 0, Wd12, P[12],
           L1, t61, 1, A, t61, 64, 64, 80, 80, 6, 0);
    conv_b(stream, A, t61, 64, nullptr, t61, 0, Wd21, P[14],
           nullptr, t61, 0, Bb, t61, 64, 64, 80, 80, 6, 1);
    conv_b(stream, Bb, t61, 64, nullptr, t61, 0, Wd22, P[16],
           A, t61, 1, A, t61, 64, 64, 80, 80, 6, 0);
    conv_b(stream, A, t61, 64, nullptr, t61, 0, Wdc, P[18],
           nullptr, t61, 0, Bb, t61, 64, 64, 80, 80, 6, 0);
    {
        dim3 gp((HW2 + 255) / 256, 6 * 64);
        pool_lrelu_k<<<gp, 256, 0, stream>>>(Bb, L2, 80, 80);
    }

    // ---------------- view loop: batched {0,1}, then {2} -------------------
    const int cv = 1;
    for (int pass = 0; pass < 2; ++pass) {
        const int vs01[2] = {0, 1};
        const int vs2[1] = {2};
        const int* vlist = pass ? vs2 : vs01;
        const int nv = pass ? 1 : 2;
        const int VB = nv * 2;

        Tab8 tcf2 = tab(0), tlf2 = tab(0), tcf1 = tab(0), tlf1 = tab(0),
             tcf0 = tab(0), tlf0 = tab(0);
        for (int i = 0; i < VB; ++i) {
            const int v = vlist[i >> 1], b = i & 1;
            tlf2.o[i] = ((long)b * 3 + v)  * 64 * HW2;
            tcf2.o[i] = ((long)b * 3 + cv) * 64 * HW2;
            tlf1.o[i] = ((long)b * 3 + v)  * 64 * HW1;
            tcf1.o[i] = ((long)b * 3 + cv) * 64 * HW1;
            tlf0.o[i] = ((long)b * 3 + v)  * 64 * HW0;
            tcf0.o[i] = ((long)b * 3 + cv) * 64 * HW0;
        }
        // ---- level 2 (40x40) ----
        offnetB(stream, offp, L2, tcf2, L2, tlf2, T1, U, OFF_A, 40, 40, VB);
        dcnB(stream, L2, tlf2, OFF_A, Wom, dcn_om_b, WPD, dcn_b,
             OM, OFF_B, 40, 40, VB);
        // ---- level 1 (80x80) ----
        offnetB(stream, offp, L1, tcf1, L1, tlf1, T1, U, OFF_B, 80, 80, VB);
        {
            dim3 gr((HW1 + 255) / 256, VB * 64);
            resize2x_k<<<gr, 256, 0, stream>>>(OFF_A, POUP, 40, 40);
        }
        offnetB(stream, mrgp, OFF_B, tab((long)64 * HW1), POUP, tab((long)64 * HW1),
                T1, U, OFF_A, 80, 80, VB);
        dcnB(stream, L1, tlf1, OFF_A, Wom, dcn_om_b, WPD, dcn_b,
             OM, OFF_B, 80, 80, VB);
        // ---- level 0 (160x160) ----
        offnetB(stream, offp, L0, tcf0, L0, tlf0, T1, U, OFF_B, 160, 160, VB);
        {
            dim3 gr((HW0 + 255) / 256, VB * 64);
            resize2x_k<<<gr, 256, 0, stream>>>(OFF_A, POUP, 80, 80);
        }
        offnetB(stream, mrgp, OFF_B, tab((long)64 * HW0), POUP, tab((long)64 * HW0),
                T1, U, OFF_A, 160, 160, VB);
        dcnB(stream, L0, tlf0, OFF_A, Wom, dcn_om_b, WPD, dcn_b,
             OM, OFF_B, 160, 160, VB);
    }
}

// Round 9
// 6258.078 us; speedup vs baseline: 1.6498x; 1.5157x over previous
//
#include <hip/hip_runtime.h>
#include <math.h>

using short8 = __attribute__((ext_vector_type(8))) short;
using f32x4  = __attribute__((ext_vector_type(4))) float;

struct Tab8 { long o[8]; };

__device__ __forceinline__ unsigned short f2bf(float f) {
    unsigned u = __builtin_bit_cast(unsigned, f);
    unsigned r = u + 0x7FFFu + ((u >> 16) & 1u);   // RNE
    return (unsigned short)(r >> 16);
}
__device__ __forceinline__ float bf2f(unsigned short h) {
    unsigned u = ((unsigned)h) << 16;
    return __builtin_bit_cast(float, u);
}

// ---------------------------------------------------------------------------
// Conv weight prep: fp32 OIHW(3x3) -> split-bf16 [cib16][Opad][tap*32 + q]
// q<16: hi(ci=cib*16+q), q>=16: lo. Zero padded.  (round-5 layout)
// ---------------------------------------------------------------------------
struct WDesc { const float* w; int Ci, O, Opad; long off; };
struct WDescs { WDesc d[18]; };

__global__ __launch_bounds__(256) void prep_w_k(WDescs ds, unsigned short* wp)
{
    const WDesc d = ds.d[blockIdx.y];
    const int ncib = (d.Ci + 15) >> 4;
    const int n = ncib * d.Opad * 288;
    const int idx = blockIdx.x * 256 + threadIdx.x;
    if (idx >= n) return;
    const int within = idx % 288;
    const int o = (idx / 288) % d.Opad;
    const int cib = idx / (288 * d.Opad);
    const int t = within >> 5, q = within & 31;
    const int ci = (cib << 4) + (q & 15);
    float v = 0.0f;
    if (o < d.O && ci < d.Ci) v = d.w[((long)o * d.Ci + ci) * 9 + t];
    const unsigned short hi = f2bf(v);
    const unsigned short lo = f2bf(v - bf2f(hi));
    wp[d.off + idx] = (q < 16) ? hi : lo;
}

// DCN weight prep: fp32 [64][576] -> split-bf16 [kb=36][o=64][q=32]
__global__ __launch_bounds__(256) void prep_dcnw_k(const float* __restrict__ w,
                                                   unsigned short* __restrict__ out)
{
    const int idx = blockIdx.x * 256 + threadIdx.x;
    if (idx >= 36 * 64 * 32) return;
    const int q = idx & 31, o = (idx >> 5) & 63, kb = idx >> 11;
    const float v = w[o * 576 + kb * 16 + (q & 15)];
    const unsigned short hi = f2bf(v);
    out[idx] = (q < 16) ? hi : f2bf(v - bf2f(hi));
}

// ---------------------------------------------------------------------------
// Split-bf16 MFMA conv3x3, SAME, NCHW, per-batch offset tables.
// Round-5 structure: weight slab staged in LDS, tid<144 halo staging.
// act: 0=none 1=relu 2=lrelu(0.01). Block: 4 waves, 64 out-ch x 16x16 px.
// ---------------------------------------------------------------------------
__global__ __launch_bounds__(256, 2) void conv_mfma_k(
    const float* __restrict__ in1, Tab8 t1, int cin1,
    const float* __restrict__ in2, Tab8 t2, int cin2,
    const unsigned short* __restrict__ wp,
    const float* __restrict__ bias,
    const float* __restrict__ res, Tab8 trr, int hasres,
    float* __restrict__ out, Tab8 to,
    int O, int H, int W, int act)
{
    __shared__ unsigned short in_t[12960];   // [18*18 px][40 stride, 32 used]
    __shared__ unsigned short w_t[18944];    // [64 co][296 stride, 288 used]
    const int tid = threadIdx.x;
    const int b = blockIdx.z;
    const int Opad = gridDim.y << 6;
    const int cobase = blockIdx.y << 6;
    const int tilesX = (W + 15) >> 4;
    const int tx = blockIdx.x % tilesX, ty = blockIdx.x / tilesX;
    const int x0 = tx << 4, y0 = ty << 4;
    const int HW = H * W;
    const int cin_tot = cin1 + cin2;
    const int ncib = (cin_tot + 15) >> 4;
    const int wv = tid >> 6, lane = tid & 63;
    const int lxx = lane & 15, kb = lane >> 4;
    const long o1 = t1.o[b], o2 = t2.o[b];

    f32x4 acc[4][4];
    #pragma unroll
    for (int i = 0; i < 4; ++i)
        #pragma unroll
        for (int j = 0; j < 4; ++j)
            acc[i][j] = (f32x4){0.f, 0.f, 0.f, 0.f};

    for (int cib = 0; cib < ncib; ++cib) {
        __syncthreads();
        const unsigned short* slab = wp + ((long)cib * Opad + cobase) * 288;
        #pragma unroll
        for (int i = 0; i < 9; ++i) {
            const int c = tid + (i << 8);
            const int row = c / 36, col = c - row * 36;
            *(short8*)&w_t[row * 296 + (col << 3)] =
                *(const short8*)(slab + row * 288 + (col << 3));
        }
        if (tid < 144) {
            const int yy = tid >> 3, rp = tid & 7;
            const int g = (cib << 4) + (rp << 1);
            const float* s0 = nullptr;
            const float* s1 = nullptr;
            if (g < cin_tot)
                s0 = (g < cin1) ? in1 + o1 + (long)g * HW
                                : in2 + o2 + (long)(g - cin1) * HW;
            if (g + 1 < cin_tot)
                s1 = (g + 1 < cin1) ? in1 + o1 + (long)(g + 1) * HW
                                    : in2 + o2 + (long)(g + 1 - cin1) * HW;
            const int gy = y0 - 1 + yy;
            const bool yok = (gy >= 0) && (gy < H);
            #pragma unroll
            for (int xx = 0; xx < 18; ++xx) {
                const int gx = x0 - 1 + xx;
                const bool ok = yok && (gx >= 0) && (gx < W);
                const float v0 = (ok && s0) ? s0[gy * W + gx] : 0.0f;
                const float v1 = (ok && s1) ? s1[gy * W + gx] : 0.0f;
                const unsigned short h0 = f2bf(v0), h1 = f2bf(v1);
                const unsigned short l0 = f2bf(v0 - bf2f(h0));
                const unsigned short l1 = f2bf(v1 - bf2f(h1));
                unsigned short* base = &in_t[(yy * 18 + xx) * 40];
                *(unsigned*)(base + (rp << 1))      = (unsigned)h0 | ((unsigned)h1 << 16);
                *(unsigned*)(base + 16 + (rp << 1)) = (unsigned)l0 | ((unsigned)l1 << 16);
            }
        }
        __syncthreads();
        #pragma unroll
        for (int ky = 0; ky < 3; ++ky) {
            #pragma unroll
            for (int kx = 0; kx < 3; ++kx) {
                const int tap = ky * 3 + kx;
                short8 a[4], b1[4], b2[4];
                #pragma unroll
                for (int mt = 0; mt < 4; ++mt)
                    a[mt] = *(const short8*)&w_t[(mt * 16 + lxx) * 296 + tap * 32 + kb * 8];
                #pragma unroll
                for (int rr = 0; rr < 4; ++rr) {
                    const int pbase = ((wv * 4 + rr + ky) * 18 + lxx + kx) * 40;
                    b1[rr] = *(const short8*)&in_t[pbase + kb * 8];
                    b2[rr] = *(const short8*)&in_t[pbase + (kb ^ 2) * 8];
                }
                #pragma unroll
                for (int mt = 0; mt < 4; ++mt)
                    #pragma unroll
                    for (int rr = 0; rr < 4; ++rr) {
                        acc[mt][rr] = __builtin_amdgcn_mfma_f32_16x16x32_bf16(
                            a[mt], b1[rr], acc[mt][rr], 0, 0, 0);
                        acc[mt][rr] = __builtin_amdgcn_mfma_f32_16x16x32_bf16(
                            a[mt], b2[rr], acc[mt][rr], 0, 0, 0);
                    }
            }
        }
    }

    const int x = x0 + lxx;
    const bool xok = (x < W);
    const long ob = to.o[b], rb = trr.o[b];
    #pragma unroll
    for (int mt = 0; mt < 4; ++mt) {
        const int col0 = cobase + mt * 16 + kb * 4;
        float bvv[4];
        #pragma unroll
        for (int j = 0; j < 4; ++j)
            bvv[j] = (col0 + j < O) ? bias[col0 + j] : 0.0f;
        #pragma unroll
        for (int rr = 0; rr < 4; ++rr) {
            const int y = y0 + wv * 4 + rr;
            if (y >= H) continue;
            #pragma unroll
            for (int j = 0; j < 4; ++j) {
                const int coj = col0 + j;
                if (coj >= O || !xok) continue;
                float v = acc[mt][rr][j] + bvv[j];
                if (hasres) v += res[rb + (long)coj * HW + (long)y * W + x];
                if (act == 1) v = fmaxf(v, 0.0f);
                else if (act == 2) v = (v >= 0.0f) ? v : 0.01f * v;
                out[ob + (long)coj * HW + (long)y * W + x] = v;
            }
        }
    }
}

// ---------------------------------------------------------------------------
// MaxPool2d(3,2,1) + LeakyReLU
// ---------------------------------------------------------------------------
__global__ __launch_bounds__(256) void pool_lrelu_k(
    const float* __restrict__ in, float* __restrict__ out, int H, int W)
{
    const int Ho = H / 2, Wo = W / 2;
    const int n = blockIdx.y;
    const int i = blockIdx.x * 256 + threadIdx.x;
    if (i >= Ho * Wo) return;
    const int ho = i / Wo, wo = i % Wo;
    const float* p = in + (long)n * H * W;
    float m = -1e30f;
    #pragma unroll
    for (int dy = 0; dy < 3; ++dy) {
        const int y = 2 * ho - 1 + dy;
        if (y < 0 || y >= H) continue;
        #pragma unroll
        for (int dx = 0; dx < 3; ++dx) {
            const int x = 2 * wo - 1 + dx;
            if (x < 0 || x >= W) continue;
            m = fmaxf(m, p[y * W + x]);
        }
    }
    out[(long)n * Ho * Wo + i] = (m >= 0.0f) ? m : 0.01f * m;
}

// Bilinear 2x upsample (half-pixel, edge clamp) then *2.0
__global__ __launch_bounds__(256) void resize2x_k(
    const float* __restrict__ in, float* __restrict__ out, int H, int W)
{
    const int Ho = 2 * H, Wo = 2 * W;
    const int n = blockIdx.y;
    const int i = blockIdx.x * 256 + threadIdx.x;
    if (i >= Ho * Wo) return;
    const int ho = i / Wo, wo = i % Wo;
    float cy = fminf(fmaxf(0.5f * (ho + 0.5f) - 0.5f, 0.0f), (float)(H - 1));
    float cx = fminf(fmaxf(0.5f * (wo + 0.5f) - 0.5f, 0.0f), (float)(W - 1));
    const int y0 = (int)cy, x0 = (int)cx;
    const int y1 = min(y0 + 1, H - 1), x1 = min(x0 + 1, W - 1);
    const float fy = cy - y0, fx = cx - x0;
    const float* p = in + (long)n * H * W;
    const float v = (1.0f - fy) * ((1.0f - fx) * p[y0 * W + x0] + fx * p[y0 * W + x1])
                  + fy * ((1.0f - fx) * p[y1 * W + x0] + fx * p[y1 * W + x1]);
    out[(long)n * Ho * Wo + i] = 2.0f * v;
}

// ---------------------------------------------------------------------------
// NCHW (strided view slot) -> NHWC [HW][64] transpose, per batch elem.
// ---------------------------------------------------------------------------
__global__ __launch_bounds__(256) void nhwc_k(
    const float* __restrict__ src, Tab8 ts, float* __restrict__ dst,
    long dstride, int HW)
{
    __shared__ float t[64][65];
    const int tid = threadIdx.x;
    const int vb = blockIdx.y;
    const int pos0 = blockIdx.x * 64;
    const float* s = src + ts.o[vb];
    float* d = dst + (long)vb * dstride;
    const int l = tid & 63, q = tid >> 6;
    #pragma unroll
    for (int i = 0; i < 16; ++i) {
        const int c = q * 16 + i;
        t[c][l] = s[(long)c * HW + pos0 + l];
    }
    __syncthreads();
    #pragma unroll
    for (int i = 0; i < 16; ++i) {
        const int p = q * 16 + i;
        d[(long)(pos0 + p) * 64 + l] = t[l][p];
    }
}

// ---------------------------------------------------------------------------
// Modulated deformable conv v2 on NHWC x. Phase A: shared records (SoA LDS);
// phase B: 8-ch vectorized gather -> split-bf16 val; phase C: MFMA K=576
// (A-frags straight from L2). Direct write into laps slot.
// ---------------------------------------------------------------------------
__global__ __launch_bounds__(256, 2) void dcn_mfma_k(
    const float* __restrict__ xT, long xtstride,     // [vb][HW][64]
    const float* __restrict__ om, long omstride,
    const unsigned short* __restrict__ wp,           // [36][64][32]
    const float* __restrict__ bias,
    float* __restrict__ outb, Tab8 toff,
    int H, int W)
{
    __shared__ unsigned short valb[9][32][40];       // 23,040 B
    __shared__ float rw0[576], rw1[576], rw2[576], rw3[576];
    __shared__ int ridx[576], rdd[576];              // total ~36.9 KB

    const int tid = threadIdx.x;
    const int vb = blockIdx.y;
    const int HW = H * W;
    const int pos0 = blockIdx.x * 32;
    const float* xv = xT + (long)vb * xtstride;
    const float* omv = om + (long)vb * omstride;
    const int lane = tid & 63, wv = tid >> 6;
    const int lxx = lane & 15, kq = lane >> 4;

    f32x4 acc[2];
    acc[0] = (f32x4){0.f, 0.f, 0.f, 0.f};
    acc[1] = (f32x4){0.f, 0.f, 0.f, 0.f};

    for (int gp = 0; gp < 4; ++gp) {
        // ---- phase A: one record per (g2,kk,pos) ----
        for (int r = tid; r < 576; r += 256) {
            const int p = r & 31;
            const int gk = r >> 5;
            const int g2 = (gk >= 9) ? 1 : 0;
            const int kk = gk - g2 * 9;
            const int g = gp * 2 + g2;
            const int pos = pos0 + p;
            const int hh = pos / W, ww = pos % W;
            const int ch = g * 9 + kk;
            const float dy = omv[(long)ch * HW + pos];
            const float dx = omv[(long)(72 + ch) * HW + pos];
            const float mv = omv[(long)(144 + ch) * HW + pos];
            const float m = 1.0f / (1.0f + expf(-mv));
            float py = dy + (float)(hh + kk / 3 - 1);
            float px = dx + (float)(ww + kk % 3 - 1);
            py = fminf(fmaxf(py, -8.0f), (float)H + 8.0f);
            px = fminf(fmaxf(px, -8.0f), (float)W + 8.0f);
            const float yf = floorf(py), xf = floorf(px);
            const float wy = py - yf, wx = px - xf;
            const int y0 = (int)yf, x0 = (int)xf;
            const int y1 = y0 + 1, x1 = x0 + 1;
            const bool yv0 = (y0 >= 0) && (y0 < H), yv1 = (y1 >= 0) && (y1 < H);
            const bool xv0_ = (x0 >= 0) && (x0 < W), xv1_ = (x1 >= 0) && (x1 < W);
            const int yc0 = min(max(y0, 0), H - 1), yc1 = min(max(y1, 0), H - 1);
            const int xc0 = min(max(x0, 0), W - 1), xc1 = min(max(x1, 0), W - 1);
            rw0[r] = (yv0 && xv0_) ? (1.f - wy) * (1.f - wx) * m : 0.f;
            rw1[r] = (yv0 && xv1_) ? (1.f - wy) * wx * m : 0.f;
            rw2[r] = (yv1 && xv0_) ? wy * (1.f - wx) * m : 0.f;
            rw3[r] = (yv1 && xv1_) ? wy * wx * m : 0.f;
            ridx[r] = yc0 * W + xc0;
            rdd[r] = (xc1 - xc0) | (((yc1 - yc0) * W) << 8);
        }
        __syncthreads();
        // ---- phase B: vectorized 8-ch gather -> split-bf16 val ----
        for (int r = tid; r < 576; r += 256) {
            const int p = r & 31;
            const int gk = r >> 5;
            const int g2 = (gk >= 9) ? 1 : 0;
            const int kk = gk - g2 * 9;
            const int g = gp * 2 + g2;
            const float w0 = rw0[r], w1 = rw1[r], w2 = rw2[r], w3 = rw3[r];
            const int dd = rdd[r];
            const long b00 = ((long)ridx[r] << 6) + (g << 3);
            const long d01 = (long)(dd & 0xff) << 6;
            const long d10 = (long)(dd >> 8) << 6;
            const float4 aA = *(const float4*)(xv + b00);
            const float4 aB = *(const float4*)(xv + b00 + 4);
            const float4 bA = *(const float4*)(xv + b00 + d01);
            const float4 bB = *(const float4*)(xv + b00 + d01 + 4);
            const float4 cA = *(const float4*)(xv + b00 + d10);
            const float4 cB = *(const float4*)(xv + b00 + d10 + 4);
            const float4 dA = *(const float4*)(xv + b00 + d10 + d01);
            const float4 dB = *(const float4*)(xv + b00 + d10 + d01 + 4);
            const int kb0 = g * 72 + kk;
#define DO_CH(VAL, C) { \
            const float v_ = (VAL); \
            const int k_ = kb0 + 9 * (C); \
            const int kbl_ = (k_ >> 4) - gp * 9; \
            const int q_ = k_ & 15; \
            const unsigned short hi_ = f2bf(v_); \
            valb[kbl_][p][q_] = hi_; \
            valb[kbl_][p][q_ + 16] = f2bf(v_ - bf2f(hi_)); }
            DO_CH(w0 * aA.x + w1 * bA.x + w2 * cA.x + w3 * dA.x, 0)
            DO_CH(w0 * aA.y + w1 * bA.y + w2 * cA.y + w3 * dA.y, 1)
            DO_CH(w0 * aA.z + w1 * bA.z + w2 * cA.z + w3 * dA.z, 2)
            DO_CH(w0 * aA.w + w1 * bA.w + w2 * cA.w + w3 * dA.w, 3)
            DO_CH(w0 * aB.x + w1 * bB.x + w2 * cB.x + w3 * dB.x, 4)
            DO_CH(w0 * aB.y + w1 * bB.y + w2 * cB.y + w3 * dB.y, 5)
            DO_CH(w0 * aB.z + w1 * bB.z + w2 * cB.z + w3 * dB.z, 6)
            DO_CH(w0 * aB.w + w1 * bB.w + w2 * cB.w + w3 * dB.w, 7)
#undef DO_CH
        }
        __syncthreads();
        // ---- phase C: MFMA; A-frags coalesced from global (L2-hot) ----
        #pragma unroll
        for (int kb = 0; kb < 9; ++kb) {
            const short8 a = *(const short8*)(
                wp + ((long)(gp * 9 + kb) * 64 + wv * 16 + lxx) * 32 + kq * 8);
            #pragma unroll
            for (int pt = 0; pt < 2; ++pt) {
                const short8 v1 = *(const short8*)&valb[kb][pt * 16 + lxx][kq * 8];
                const short8 v2 = *(const short8*)&valb[kb][pt * 16 + lxx][(kq ^ 2) * 8];
                acc[pt] = __builtin_amdgcn_mfma_f32_16x16x32_bf16(a, v1, acc[pt], 0, 0, 0);
                acc[pt] = __builtin_amdgcn_mfma_f32_16x16x32_bf16(a, v2, acc[pt], 0, 0, 0);
            }
        }
        __syncthreads();
    }
    float* ov = outb + toff.o[vb];
    #pragma unroll
    for (int pt = 0; pt < 2; ++pt)
        #pragma unroll
        for (int j = 0; j < 4; ++j) {
            const int o = wv * 16 + kq * 4 + j;
            const int p = pt * 16 + lxx;
            ov[(long)o * HW + pos0 + p] = acc[pt][j] + bias[o];
        }
}

// ---------------------------------------------------------------------------
// Host orchestration
// ---------------------------------------------------------------------------
namespace {

struct MOff {
    const unsigned short *c1w; const float* c1b;
    const unsigned short *rw1; const float* rb1;
    const unsigned short *rw2; const float* rb2;
    const unsigned short *c2w; const float* c2b;
};

inline Tab8 tab(long stride) {
    Tab8 t;
    for (int i = 0; i < 8; ++i) t.o[i] = (long)i * stride;
    return t;
}

inline void conv_b(hipStream_t s,
                   const float* i1, Tab8 t1, int c1,
                   const float* i2, Tab8 t2, int c2,
                   const unsigned short* w, const float* bias,
                   const float* res, Tab8 trr, int hasres,
                   float* out, Tab8 to,
                   int O, int Opad, int H, int W, int B, int act)
{
    dim3 grid(((H + 15) / 16) * ((W + 15) / 16), Opad / 64, B);
    conv_mfma_k<<<grid, 256, 0, s>>>(i1, t1, c1, i2, t2, c2, w, bias,
                                     res, trr, hasres, out, to, O, H, W, act);
}

inline void offnetB(hipStream_t s, const MOff& p,
                    const float* cfb, Tab8 tcf, const float* lfb, Tab8 tlf,
                    float* t1, float* u, float* outp, int H, int W, int B)
{
    const long hw = (long)H * W;
    const Tab8 tz = tab(64 * hw);
    conv_b(s, cfb, tcf, 64, lfb, tlf, 64, p.c1w, p.c1b,
           nullptr, tz, 0, t1, tz, 64, 64, H, W, B, 2);
    for (int r = 0; r < 2; ++r) {
        conv_b(s, t1, tz, 64, nullptr, tz, 0, p.rw1, p.rb1,
               nullptr, tz, 0, u, tz, 64, 64, H, W, B, 1);
        conv_b(s, u, tz, 64, nullptr, tz, 0, p.rw2, p.rb2,
               t1, tz, 1, t1, tz, 64, 64, H, W, B, 0);
    }
    conv_b(s, t1, tz, 64, nullptr, tz, 0, p.c2w, p.c2b,
           nullptr, tz, 0, outp, tz, 64, 64, H, W, B, 2);
}

// NHWC transpose + om conv + fused dcn (direct laps write), chunked for ws.
inline void dcnB(hipStream_t s, float* lapbase, Tab8 tlf,
                 const float* feat,
                 const unsigned short* Wom, const float* omb,
                 const unsigned short* Wdcn, const float* dcnb,
                 float* om, float* xt, int H, int W, int VB)
{
    const long hw = (long)H * W;
    const long SZf = 64L * 25600;
    int cmax = (int)((8L * SZf) / (216 * hw));           // om capacity (8 SZ)
    const int cx = (int)((4L * SZf) / (64 * hw));        // xt capacity (4 SZ)
    if (cx < cmax) cmax = cx;
    if (cmax > VB) cmax = VB;
    if (cmax < 1) cmax = 1;
    for (int c0 = 0; c0 < VB; c0 += cmax) {
        const int nc = (VB - c0 < cmax) ? (VB - c0) : cmax;
        Tab8 tfeat = tab(0), tx = tab(0);
        for (int i = 0; i < nc; ++i) {
            tfeat.o[i] = (long)(c0 + i) * 64 * hw;
            tx.o[i]    = tlf.o[c0 + i];
        }
        dim3 gt((int)(hw / 64), nc);
        nhwc_k<<<gt, 256, 0, s>>>(lapbase, tx, xt, 64 * hw, (int)hw);
        conv_b(s, feat, tfeat, 64, nullptr, tfeat, 0, Wom, omb,
               nullptr, tfeat, 0, om, tab(216 * hw), 216, 256, H, W, nc, 0);
        dim3 gd((int)(hw / 32), nc);
        dcn_mfma_k<<<gd, 256, 0, s>>>(xt, 64 * hw, om, 216 * hw, Wdcn, dcnb,
                                      lapbase, tx, H, W);
    }
}

} // namespace

extern "C" void kernel_launch(void* const* d_in, const int* in_sizes, int n_in,
                              void* d_out, int out_size, void* d_ws, size_t ws_size,
                              hipStream_t stream)
{
    (void)in_sizes; (void)n_in; (void)out_size; (void)ws_size;
    const float* P[39];
    for (int k = 0; k < 39; ++k) P[k] = (const float*)d_in[k];
    const float* images = P[0];

    const int HW0 = 160 * 160, HW1 = 80 * 80, HW2 = 40 * 40;
    float* L0 = (float*)d_out;
    float* L1 = L0 + (long)6 * 64 * HW0;
    float* L2 = L1 + (long)6 * 64 * HW1;

    // ---- workspace: 16*SZ floats (~105 MB) + weights (~3.5 MB) ----
    const long SZ = (long)64 * HW0;
    float* ws = (float*)d_ws;
    float* OFF_A = ws;                        // [0, 4SZ)   po chain
    float* OFF_B = ws + 4 * SZ;               // [4, 8SZ)   offnet-stage / XT
    float* POUP  = ws + 8 * SZ;               // [8, 12SZ)  po_up*2; U scratch
    float* T1    = ws + 12 * SZ;              // [12, 16SZ) offnet hidden
    float* U     = POUP;
    float* OM    = ws + 8 * SZ;               // overlays POUP+T1 (8SZ cap)
    float* A     = ws;                        // features phase (6SZ)
    float* Bb    = ws + 6 * SZ;               // features phase (6SZ)
    unsigned short* WP = (unsigned short*)(ws + 16 * SZ);

    // ---- weight prep ----
    const int widx[18] = {1,3,5,7,9,11,13,15,17,19,21,23,25,27,29,31,33,35};
    const int wci[18]  = {3,64,64,64,64,64,64,64,64,128,64,64,64,128,64,64,64,64};
    const int wo_[18]  = {64,64,64,64,64,64,64,64,64,64,64,64,64,64,64,64,64,216};
    WDescs ds;
    long off = 0;
    long woff[18];
    for (int i = 0; i < 18; ++i) {
        const int opad = (wo_[i] + 63) / 64 * 64;
        const int ncib = (wci[i] + 15) / 16;
        ds.d[i].w = P[widx[i]]; ds.d[i].Ci = wci[i]; ds.d[i].O = wo_[i];
        ds.d[i].Opad = opad; ds.d[i].off = off;
        woff[i] = off;
        off += (long)ncib * opad * 288;
    }
    unsigned short* WPD = WP + off;           // dcn weights [36][64][32]
    prep_w_k<<<dim3(1152, 18), 256, 0, stream>>>(ds, WP);
    prep_dcnw_k<<<dim3(288), 256, 0, stream>>>(P[37], WPD);

    const unsigned short* Wc0a  = WP + woff[0];
    const unsigned short* Wc0r1 = WP + woff[1];
    const unsigned short* Wc0r2 = WP + woff[2];
    const unsigned short* Wc0b  = WP + woff[3];
    const unsigned short* Wd11  = WP + woff[4];
    const unsigned short* Wd12  = WP + woff[5];
    const unsigned short* Wd21  = WP + woff[6];
    const unsigned short* Wd22  = WP + woff[7];
    const unsigned short* Wdc   = WP + woff[8];
    MOff offp = {WP + woff[9],  P[20], WP + woff[10], P[22],
                 WP + woff[11], P[24], WP + woff[12], P[26]};
    MOff mrgp = {WP + woff[13], P[28], WP + woff[14], P[30],
                 WP + woff[15], P[32], WP + woff[16], P[34]};
    const unsigned short* Wom = WP + woff[17];
    const float* dcn_om_b = P[36];
    const float* dcn_b = P[38];

    // ---------------- feature extraction (B = 6, contiguous) --------------
    const Tab8 ti = tab((long)3 * HW0);
    const Tab8 t60 = tab((long)64 * HW0);
    const Tab8 t61 = tab((long)64 * HW1);
    conv_b(stream, images, ti, 3, nullptr, t60, 0, Wc0a, P[2],
           nullptr, t60, 0, A, t60, 64, 64, 160, 160, 6, 0);
    conv_b(stream, A, t60, 64, nullptr, t60, 0, Wc0r1, P[4],
           nullptr, t60, 0, Bb, t60, 64, 64, 160, 160, 6, 1);
    conv_b(stream, Bb, t60, 64, nullptr, t60, 0, Wc0r2, P[6],
           A, t60, 1, A, t60, 64, 64, 160, 160, 6, 0);
    conv_b(stream, A, t60, 64, nullptr, t60, 0, Wc0b, P[8],
           nullptr, t60, 0, L0, t60, 64, 64, 160, 160, 6, 2);

    conv_b(stream, L0, t60, 64, nullptr, t60, 0, Wd11, P[10],
           nullptr, t60, 0, Bb, t60, 64, 64, 160, 160, 6, 1);
    conv_b(stream, Bb, t60, 64, nullptr, t60, 0, Wd12, P[12],
           L0, t60, 1, A, t60, 64, 64, 160, 160, 6, 0);
    conv_b(stream, A, t60, 64, nullptr, t60, 0, Wd21, P[14],
           nullptr, t60, 0, Bb, t60, 64, 64, 160, 160, 6, 1);
    conv_b(stream, Bb, t60, 64, nullptr, t60, 0, Wd22, P[16],
           A, t60, 1, A, t60, 64, 64, 160, 160, 6, 0);
    conv_b(stream, A, t60, 64, nullptr, t60, 0, Wdc, P[18],
           nullptr, t60, 0, Bb, t60, 64, 64, 160, 160, 6, 0);
    {
        dim3 gp((HW1 + 255) / 256, 6 * 64);
        pool_lrelu_k<<<gp, 256, 0, stream>>>(Bb, L1, 160, 160);
    }
    conv_b(stream, L1, t61, 64, nullptr, t61, 0, Wd11, P[10],
           nullptr, t61, 0, Bb, t61, 64, 64, 80, 80, 6, 1);
    conv_b(stream, Bb, t61, 64, nullptr, t61, 0, Wd12, P[12],
           L1, t61, 1, A, t61, 64, 64, 80, 80, 6, 0);
    conv_b(stream, A, t61, 64, nullptr, t61, 0, Wd21, P[14],
           nullptr, t61, 0, Bb, t61, 64, 64, 80, 80, 6, 1);
    conv_b(stream, Bb, t61, 64, nullptr, t61, 0, Wd22, P[16],
           A, t61, 1, A, t61, 64, 64, 80, 80, 6, 0);
    conv_b(stream, A, t61, 64, nullptr, t61, 0, Wdc, P[18],
           nullptr, t61, 0, Bb, t61, 64, 64, 80, 80, 6, 0);
    {
        dim3 gp((HW2 + 255) / 256, 6 * 64);
        pool_lrelu_k<<<gp, 256, 0, stream>>>(Bb, L2, 80, 80);
    }

    // ---------------- view loop: batched {0,1}, then {2} -------------------
    const int cv = 1;
    for (int pass = 0; pass < 2; ++pass) {
        const int vs01[2] = {0, 1};
        const int vs2[1] = {2};
        const int* vlist = pass ? vs2 : vs01;
        const int nv = pass ? 1 : 2;
        const int VB = nv * 2;

        Tab8 tcf2 = tab(0), tlf2 = tab(0), tcf1 = tab(0), tlf1 = tab(0),
             tcf0 = tab(0), tlf0 = tab(0);
        for (int i = 0; i < VB; ++i) {
            const int v = vlist[i >> 1], b = i & 1;
            tlf2.o[i] = ((long)b * 3 + v)  * 64 * HW2;
            tcf2.o[i] = ((long)b * 3 + cv) * 64 * HW2;
            tlf1.o[i] = ((long)b * 3 + v)  * 64 * HW1;
            tcf1.o[i] = ((long)b * 3 + cv) * 64 * HW1;
            tlf0.o[i] = ((long)b * 3 + v)  * 64 * HW0;
            tcf0.o[i] = ((long)b * 3 + cv) * 64 * HW0;
        }
        // ---- level 2 (40x40) ----
        offnetB(stream, offp, L2, tcf2, L2, tlf2, T1, U, OFF_A, 40, 40, VB);
        dcnB(stream, L2, tlf2, OFF_A, Wom, dcn_om_b, WPD, dcn_b,
             OM, OFF_B, 40, 40, VB);
        // ---- level 1 (80x80) ----
        offnetB(stream, offp, L1, tcf1, L1, tlf1, T1, U, OFF_B, 80, 80, VB);
        {
            dim3 gr((HW1 + 255) / 256, VB * 64);
            resize2x_k<<<gr, 256, 0, stream>>>(OFF_A, POUP, 40, 40);
        }
        offnetB(stream, mrgp, OFF_B, tab((long)64 * HW1), POUP, tab((long)64 * HW1),
                T1, U, OFF_A, 80, 80, VB);
        dcnB(stream, L1, tlf1, OFF_A, Wom, dcn_om_b, WPD, dcn_b,
             OM, OFF_B, 80, 80, VB);
        // ---- level 0 (160x160) ----
        offnetB(stream, offp, L0, tcf0, L0, tlf0, T1, U, OFF_B, 160, 160, VB);
        {
            dim3 gr((HW0 + 255) / 256, VB * 64);
            resize2x_k<<<gr, 256, 0, stream>>>(OFF_A, POUP, 80, 80);
        }
        offnetB(stream, mrgp, OFF_B, tab((long)64 * HW0), POUP, tab((long)64 * HW0),
                T1, U, OFF_A, 160, 160, VB);
        dcnB(stream, L0, tlf0, OFF_A, Wom, dcn_om_b, WPD, dcn_b,
             OM, OFF_B, 160, 160, VB);
    }
}